// Round 6
// baseline (511.072 us; speedup 1.0000x reference)
//
#include <hip/hip_runtime.h>
#include <math.h>

#define TTOT 512
#define CCH 8
#define FFR 257
#define AAH 320
#define NBF 2056      // B*F
#define BF2 2112      // padded to 33*64
#define NTIL 32       // t tiles in k_psd grid
#define TTILE 16
#define NG 144        // Hermitian-unique partial values per bf: (10+10+16)*4
#define EPSF 1e-15f
#define WSB (FFR * 8) // ws complex elements per b

// ---------------- workspace layout (floats), total ~49.6 MB ----------------
#define OFF_MBS 0                                   // [NBF][512]
#define OFF_MBN (OFF_MBS + NBF * 512)               // [NBF][512]
#define OFF_PART (OFF_MBN + NBF * 512)              // [NTIL][NG][BF2]
#define OFF_PSDS (OFF_PART + NTIL * NG * BF2)       // [NBF][8][8][2]
#define OFF_PSDN (OFF_PSDS + NBF * 128)
#define OFF_E (OFF_PSDN + NBF * 128)                // [64]
#define OFF_WS (OFF_E + 64)                         // [NBF][8][2]

// diag-quadrant Hermitian-unique pairs (i<=j within 4)
__device__ __constant__ int d_pi[10] = {0,0,0,0,1,1,1,2,2,3};
__device__ __constant__ int d_pj[10] = {0,1,2,3,1,2,3,2,3,3};

// K_mask: block(128 thr) per bf. m = mean_c(mask); m /= (sum_t m + EPS).
__global__ __launch_bounds__(128) void k_mask(
    const float* __restrict__ mask_s, const float* __restrict__ mask_n,
    float* __restrict__ mbar_s, float* __restrict__ mbar_n) {
  int bf = blockIdx.x;
  int tid = threadIdx.x;
  int lane = tid & 63, wv = tid >> 6;
  const float4* ms = (const float4*)(mask_s + (size_t)bf * CCH * TTOT);
  const float4* mn = (const float4*)(mask_n + (size_t)bf * CCH * TTOT);
  float4 ss = make_float4(0.f, 0.f, 0.f, 0.f);
  float4 sn = make_float4(0.f, 0.f, 0.f, 0.f);
#pragma unroll
  for (int c = 0; c < 8; ++c) {
    float4 a = ms[c * 128 + tid];
    ss.x += a.x; ss.y += a.y; ss.z += a.z; ss.w += a.w;
    float4 b = mn[c * 128 + tid];
    sn.x += b.x; sn.y += b.y; sn.z += b.z; sn.w += b.w;
  }
  float tots = (ss.x + ss.y) + (ss.z + ss.w);
  float totn = (sn.x + sn.y) + (sn.z + sn.w);
#pragma unroll
  for (int off = 32; off > 0; off >>= 1) {
    tots += __shfl_down(tots, off);
    totn += __shfl_down(totn, off);
  }
  __shared__ float reds[2], redn[2];
  if (lane == 0) { reds[wv] = tots; redn[wv] = totn; }
  __syncthreads();
  float invs = 0.125f / ((reds[0] + reds[1]) * 0.125f + EPSF);
  float invn = 0.125f / ((redn[0] + redn[1]) * 0.125f + EPSF);
  ((float4*)(mbar_s + (size_t)bf * TTOT))[tid] =
      make_float4(ss.x * invs, ss.y * invs, ss.z * invs, ss.w * invs);
  ((float4*)(mbar_n + (size_t)bf * TTOT))[tid] =
      make_float4(sn.x * invn, sn.y * invn, sn.z * invn, sn.w * invn);
}

// K_psd: lane=bf, 3 waves: wq=0 -> quadrant(0,0) i<=j (10 pairs),
// wq=1 -> (4,4) i<=j (10 pairs), wq=2 -> (0,4) full (16 pairs).
// (4,0) derived by conjugate transpose in k_reduce. TTILE=16, grid (33,32).
__global__ __launch_bounds__(192) void k_psd(
    const float* __restrict__ dr, const float* __restrict__ di,
    const float* __restrict__ mbar_s, const float* __restrict__ mbar_n,
    float* __restrict__ partial) {
  __shared__ float lms[64][TTILE + 1];
  __shared__ float lmn[64][TTILE + 1];
  int tid = threadIdx.x;
  int lane = tid & 63, wq = tid >> 6;
  int bfb = blockIdx.x, ttile = blockIdx.y;
  int t0 = ttile * TTILE;

  // stage mbar tile [64 bf][16 t] both masks
  for (int i = tid; i < 512; i += 192) {
    int msel = i >> 8, rem = i & 255;
    int bfi = rem >> 2, qo = (rem & 3) * 4;
    int bfg = bfb * 64 + bfi; if (bfg > NBF - 1) bfg = NBF - 1;
    const float* src = (msel ? mbar_n : mbar_s) + (size_t)bfg * TTOT + t0 + qo;
    float4 v = *(const float4*)src;
    float (*l)[TTILE + 1] = msel ? lmn : lms;
    l[bfi][qo + 0] = v.x; l[bfi][qo + 1] = v.y;
    l[bfi][qo + 2] = v.z; l[bfi][qo + 3] = v.w;
  }

  int bf = bfb * 64 + lane; if (bf > NBF - 1) bf = NBF - 1;
  int b = bf / FFR, f = bf - b * FFR;
  const float* br = dr + (size_t)b * TTOT * CCH * FFR + (size_t)t0 * CCH * FFR + f;
  const float* bi = di + (size_t)b * TTOT * CCH * FFR + (size_t)t0 * CCH * FFR + f;
  __syncthreads();

  size_t pbase = ((size_t)ttile * NG) * BF2 + bfb * 64 + lane;

  if (wq < 2) {
    // diag quadrant rows r0..r0+3; buf[0..3]=re, buf[4..7]=im
    int r0 = wq * 4;
    float acc[40];
#pragma unroll
    for (int g = 0; g < 40; ++g) acc[g] = 0.f;
    float A[8], B[8];
    auto LOADX = [&](float (&buf)[8], int tt) {
      const float* pr = br + (size_t)tt * (CCH * FFR);
      const float* pi_ = bi + (size_t)tt * (CCH * FFR);
#pragma unroll
      for (int k = 0; k < 4; ++k) {
        buf[k] = pr[(r0 + k) * FFR];
        buf[4 + k] = pi_[(r0 + k) * FFR];
      }
    };
    auto FMAX = [&](float (&buf)[8], int tt) {
      float m_s = lms[lane][tt];
      float m_n = lmn[lane][tt];
#pragma unroll
      for (int p = 0; p < 10; ++p) {
        int i = d_pi[p], j = d_pj[p];
        float pre = buf[i] * buf[j] + buf[4 + i] * buf[4 + j];
        float pim = buf[4 + i] * buf[j] - buf[i] * buf[4 + j];
        acc[p * 4 + 0] += m_s * pre;
        acc[p * 4 + 1] += m_s * pim;
        acc[p * 4 + 2] += m_n * pre;
        acc[p * 4 + 3] += m_n * pim;
      }
    };
    LOADX(A, 0); LOADX(B, 1);
#pragma unroll
    for (int tt = 0; tt < TTILE; tt += 2) {
      FMAX(A, tt);
      if (tt + 2 < TTILE) LOADX(A, tt + 2);
      FMAX(B, tt + 1);
      if (tt + 3 < TTILE) LOADX(B, tt + 3);
    }
    size_t base = pbase + (size_t)(wq * 40) * BF2;
#pragma unroll
    for (int g = 0; g < 40; ++g) partial[base + (size_t)g * BF2] = acc[g];
  } else {
    // off-diag quadrant (rows 0..3) x (cols 4..7); buf[0..7]=re rows, [8..15]=im
    float acc[64];
#pragma unroll
    for (int g = 0; g < 64; ++g) acc[g] = 0.f;
    float A[16], B[16];
    auto LOADX = [&](float (&buf)[16], int tt) {
      const float* pr = br + (size_t)tt * (CCH * FFR);
      const float* pi_ = bi + (size_t)tt * (CCH * FFR);
#pragma unroll
      for (int k = 0; k < 8; ++k) {
        buf[k] = pr[k * FFR];
        buf[8 + k] = pi_[k * FFR];
      }
    };
    auto FMAX = [&](float (&buf)[16], int tt) {
      float m_s = lms[lane][tt];
      float m_n = lmn[lane][tt];
#pragma unroll
      for (int i = 0; i < 4; ++i)
#pragma unroll
        for (int jj = 0; jj < 4; ++jj) {
          int p = i * 4 + jj;
          float pre = buf[i] * buf[4 + jj] + buf[8 + i] * buf[12 + jj];
          float pim = buf[8 + i] * buf[4 + jj] - buf[i] * buf[12 + jj];
          acc[p * 4 + 0] += m_s * pre;
          acc[p * 4 + 1] += m_s * pim;
          acc[p * 4 + 2] += m_n * pre;
          acc[p * 4 + 3] += m_n * pim;
        }
    };
    LOADX(A, 0); LOADX(B, 1);
#pragma unroll
    for (int tt = 0; tt < TTILE; tt += 2) {
      FMAX(A, tt);
      if (tt + 2 < TTILE) LOADX(A, tt + 2);
      FMAX(B, tt + 1);
      if (tt + 3 < TTILE) LOADX(B, tt + 3);
    }
    size_t base = pbase + (size_t)80 * BF2;
#pragma unroll
    for (int g = 0; g < 64; ++g) partial[base + (size_t)g * BF2] = acc[g];
  }
}

// K_reduce: grid (33, 36); wave = one g over NTIL tiles; lane = bf.
// Hermitian expansion: write (i,j) and conj to (j,i).
__global__ __launch_bounds__(256) void k_reduce(
    const float* __restrict__ partial, float* __restrict__ psd_s,
    float* __restrict__ psd_n) {
  int lane = threadIdx.x & 63, wv = threadIdx.x >> 6;
  int bfb = blockIdx.x;
  int g = blockIdx.y * 4 + wv;  // 0..143
  int bf = bfb * 64 + lane;
  const float* src = partial + (size_t)g * BF2 + bfb * 64 + lane;
  float s = 0.f;
#pragma unroll
  for (int nt = 0; nt < NTIL; ++nt) s += src[(size_t)nt * NG * BF2];
  if (bf < NBF) {
    int i, j, comp;
    if (g < 80) {
      int q = g / 40, l = g - q * 40, p = l >> 2;
      comp = l & 3;
      i = d_pi[p] + q * 4; j = d_pj[p] + q * 4;
    } else {
      int l = g - 80, p = l >> 2;
      comp = l & 3;
      i = p >> 2; j = 4 + (p & 3);
    }
    float* dst = (comp < 2) ? psd_s : psd_n;
    int ci = comp & 1;
    size_t base = (size_t)bf * 128;
    dst[base + (i * 8 + j) * 2 + ci] = s;
    dst[base + (j * 8 + i) * 2 + ci] = ci ? -s : s;
  }
}

// K2: grid (64 bc, 5 a-chunks) x 64 thr. feat in LDS, partial MLP dot,
// tanh, gvec, wave-reduce, atomicAdd into e[bc] (zeroed by memsetAsync).
__global__ __launch_bounds__(64) void k2_attn(
    const float* __restrict__ psd_s, const float* __restrict__ mlp_w,
    const float* __restrict__ mlp_b, const float* __restrict__ gvec_w,
    float* __restrict__ e_out) {
  __shared__ float feat[FFR];
  int bc = blockIdx.x;
  int ach = blockIdx.y;
  int b = bc >> 3, c = bc & 7;
  int tid = threadIdx.x;
  for (int f = tid; f < FFR; f += 64) {
    const float* p = psd_s + (((size_t)(b * FFR + f)) * 8 + c) * 16;
    float sre = 0.f, sim = 0.f;
#pragma unroll
    for (int e = 0; e < 8; ++e) {
      if (e != c) { sre += p[e * 2]; sim += p[e * 2 + 1]; }
    }
    feat[f] = sqrtf(sre * sre + sim * sim) * (1.0f / 7.0f);
  }
  __syncthreads();
  int a = ach * 64 + tid;
  float acc = mlp_b[a];
#pragma unroll 8
  for (int f = 0; f < FFR; ++f) acc += feat[f] * mlp_w[f * AAH + a];
  float v = tanhf(acc) * gvec_w[a];
#pragma unroll
  for (int off = 32; off > 0; off >>= 1) v += __shfl_down(v, off);
  if (tid == 0) atomicAdd(&e_out[bc], v);
}

// K3: one wave per (b,f); barrier-free Gauss-Jordan via shuffles; fused softmax.
__global__ __launch_bounds__(256) void k3_mvdr(
    const float* __restrict__ psd_s, const float* __restrict__ psd_n,
    const float* __restrict__ e_in, const float* __restrict__ gvec_b,
    float* __restrict__ ws) {
  int lane = threadIdx.x & 63, wv = threadIdx.x >> 6;
  int bf = blockIdx.x * 4 + wv;  // 514*4 == 2056 exact
  int b = bf / FFR;
  int r = lane >> 3, c = lane & 7;
  float2 n = ((const float2*)(psd_n + (size_t)bf * 128))[lane];
  float2 s = ((const float2*)(psd_s + (size_t)bf * 128))[lane];

#pragma unroll
  for (int k = 0; k < 8; ++k) {
    float pvre = __shfl(n.x, k * 9), pvim = __shfl(n.y, k * 9);
    float dinv = 1.f / (pvre * pvre + pvim * pvim);
    float pire = pvre * dinv, piim = -pvim * dinv;
    if (r == k) {
      float2 nn = n, ss = s;
      n.x = nn.x * pire - nn.y * piim; n.y = nn.x * piim + nn.y * pire;
      s.x = ss.x * pire - ss.y * piim; s.y = ss.x * piim + ss.y * pire;
    }
    float fre = __shfl(n.x, r * 8 + k), fim = __shfl(n.y, r * 8 + k);
    float pnre = __shfl(n.x, k * 8 + c), pnim = __shfl(n.y, k * 8 + c);
    float psre = __shfl(s.x, k * 8 + c), psim = __shfl(s.y, k * 8 + c);
    if (r != k) {
      n.x -= fre * pnre - fim * pnim; n.y -= fre * pnim + fim * pnre;
      s.x -= fre * psre - fim * psim; s.y -= fre * psim + fim * psre;
    }
  }
  float trx = (r == c) ? s.x : 0.f, tryy = (r == c) ? s.y : 0.f;
#pragma unroll
  for (int off = 1; off < 64; off <<= 1) {
    trx += __shfl_xor(trx, off);
    tryy += __shfl_xor(tryy, off);
  }
  float val = 2.f * (e_in[b * 8 + c] + gvec_b[0]);
  float mx = val;
#pragma unroll
  for (int off = 1; off < 8; off <<= 1) mx = fmaxf(mx, __shfl_xor(mx, off));
  float pe = expf(val - mx);
  float psum = pe;
#pragma unroll
  for (int off = 1; off < 8; off <<= 1) psum += __shfl_xor(psum, off);
  float uc = pe / psum;
  float wre = s.x * uc, wim = s.y * uc;
#pragma unroll
  for (int off = 1; off < 8; off <<= 1) {
    wre += __shfl_xor(wre, off);
    wim += __shfl_xor(wim, off);
  }
  float tre = trx + EPSF, tim = tryy;
  float d2 = 1.f / (tre * tre + tim * tim);
  float owre = (wre * tre + wim * tim) * d2;
  float owim = (wim * tre - wre * tim) * d2;
  if (c == 0) ((float2*)ws)[(size_t)bf * 8 + r] = make_float2(owre, owim);
}

// K4: block = (b, 4-t tile); stage ws[b] in padded LDS; coalesced f reads.
__global__ __launch_bounds__(256) void k4_beam(
    const float* __restrict__ dr, const float* __restrict__ di,
    const float* __restrict__ ws, float* __restrict__ out) {
  __shared__ float2 wsp[FFR * 9];
  int b = blockIdx.y;
  int t0 = blockIdx.x * 4;
  int tid = threadIdx.x;
  const float2* wsg = (const float2*)ws + (size_t)b * WSB;
  for (int i = tid; i < FFR * 8; i += 256) {
    int f = i >> 3, c = i & 7;
    wsp[f * 9 + c] = wsg[i];
  }
  __syncthreads();
  for (int ts = 0; ts < 4; ++ts) {
    int t = t0 + ts;
    const float* drb = dr + (size_t)(b * TTOT + t) * (CCH * FFR);
    const float* dib = di + (size_t)(b * TTOT + t) * (CCH * FFR);
    for (int f = tid; f < FFR; f += 256) {
      float are = 0.f, aim = 0.f;
#pragma unroll
      for (int c = 0; c < 8; ++c) {
        float xre = drb[c * FFR + f];
        float xim = dib[c * FFR + f];
        float2 w = wsp[f * 9 + c];
        are += w.x * xre + w.y * xim;
        aim += w.x * xim - w.y * xre;
      }
      ((float2*)out)[(size_t)(b * TTOT + t) * FFR + f] = make_float2(are, aim);
    }
  }
}

extern "C" void kernel_launch(void* const* d_in, const int* in_sizes, int n_in,
                              void* d_out, int out_size, void* d_ws, size_t ws_size,
                              hipStream_t stream) {
  const float* dr = (const float*)d_in[0];
  const float* di = (const float*)d_in[1];
  const float* mask_s = (const float*)d_in[2];
  const float* mask_n = (const float*)d_in[3];
  const float* mlp_w = (const float*)d_in[4];
  const float* mlp_b = (const float*)d_in[5];
  const float* gvec_w = (const float*)d_in[6];
  const float* gvec_b = (const float*)d_in[7];
  float* out = (float*)d_out;

  float* wsf = (float*)d_ws;
  float* mbar_s = wsf + OFF_MBS;
  float* mbar_n = wsf + OFF_MBN;
  float* part = wsf + OFF_PART;
  float* psd_s = wsf + OFF_PSDS;
  float* psd_n = wsf + OFF_PSDN;
  float* e_arr = wsf + OFF_E;
  float* wsv = wsf + OFF_WS;

  hipLaunchKernelGGL(k_mask, dim3(NBF), dim3(128), 0, stream,
                     mask_s, mask_n, mbar_s, mbar_n);
  hipLaunchKernelGGL(k_psd, dim3(33, NTIL), dim3(192), 0, stream,
                     dr, di, mbar_s, mbar_n, part);
  hipLaunchKernelGGL(k_reduce, dim3(33, 36), dim3(256), 0, stream,
                     part, psd_s, psd_n);
  hipMemsetAsync((void*)e_arr, 0, 64 * sizeof(float), stream);
  hipLaunchKernelGGL(k2_attn, dim3(64, 5), dim3(64), 0, stream,
                     psd_s, mlp_w, mlp_b, gvec_w, e_arr);
  hipLaunchKernelGGL(k3_mvdr, dim3(514), dim3(256), 0, stream,
                     psd_s, psd_n, e_arr, gvec_b, wsv);
  hipLaunchKernelGGL(k4_beam, dim3(128, 8), dim3(256), 0, stream, dr, di, wsv, out);
}